// Round 2
// baseline (52878.674 us; speedup 1.0000x reference)
//
#include <hip/hip_runtime.h>
#include <cstdint>

#define NROWS 10000
#define DIM   784
#define CAND  150
#define MOUT  10
#define KMAX  64
#define TOT_W 117600   // DIM*CAND
#define TOT_B 150
#define GEMM_BLOCKS 157   // ceil(10000/64)
#define NB256 40          // ceil(10000/256)

// ---------------- Threefry-2x32 (exact JAX semantics) ----------------
#define RND_(r) { x0 += x1; x1 = (x1 << r) | (x1 >> (32 - r)); x1 ^= x0; }

__host__ __device__ inline void threefry2x32(uint32_t k0, uint32_t k1,
                                             uint32_t c0, uint32_t c1,
                                             uint32_t* o0, uint32_t* o1) {
  uint32_t ks2 = 0x1BD11BDAu ^ k0 ^ k1;
  uint32_t x0 = c0 + k0, x1 = c1 + k1;
  RND_(13) RND_(15) RND_(26) RND_(6)
  x0 += k1;  x1 += ks2 + 1u;
  RND_(17) RND_(29) RND_(16) RND_(24)
  x0 += ks2; x1 += k0 + 2u;
  RND_(13) RND_(15) RND_(26) RND_(6)
  x0 += k0;  x1 += k1 + 3u;
  RND_(17) RND_(29) RND_(16) RND_(24)
  x0 += k1;  x1 += ks2 + 4u;
  RND_(13) RND_(15) RND_(26) RND_(6)
  x0 += ks2; x1 += k0 + 5u;
  *o0 = x0; *o1 = x1;
}

__device__ inline float uni01(uint32_t bits) {
  uint32_t fb = (bits >> 9) | 0x3F800000u;      // mantissa trick: [1,2)
  return __uint_as_float(fb) - 1.0f;            // [0,1)
}

__device__ inline float scale_of(int j) {
  return (j < 50) ? 0.5f : ((j < 100) ? 1.0f : 5.0f);
}

// ---------------- kernels ----------------
__global__ __launch_bounds__(256) void init_e_kern(const float* __restrict__ Y, float* __restrict__ e) {
  int i = blockIdx.x * 256 + threadIdx.x;
  if (i < NROWS * MOUT) e[i] = Y[i];
}

// jax_threefry_partitionable=True semantics: element f -> counter (0, f), bits = o0 ^ o1
__global__ __launch_bounds__(256) void gen_rand_kern(float* __restrict__ Wr, float* __restrict__ br,
                                                     uint32_t kw0, uint32_t kw1,
                                                     uint32_t kb0, uint32_t kb1) {
  int f = blockIdx.x * 256 + threadIdx.x;
  if (f < TOT_W) {
    uint32_t o0, o1;
    threefry2x32(kw0, kw1, 0u, (uint32_t)f, &o0, &o1);
    float u = uni01(o0 ^ o1);
    int j = f % CAND;
    Wr[f] = scale_of(j) * (2.0f * u - 1.0f);
  } else if (f < TOT_W + TOT_B) {
    int g = f - TOT_W;
    uint32_t o0, o1;
    threefry2x32(kb0, kb1, 0u, (uint32_t)g, &o0, &o1);
    float u = uni01(o0 ^ o1);
    br[g] = scale_of(g) * (2.0f * u - 1.0f);
  }
}

// h = sigmoid(X@W + b); per-(block,candidate) partials of sum(h*h) and e^T h
__global__ __launch_bounds__(192) void gemm_h_kern(const float* __restrict__ X, const float* __restrict__ e,
                                                   const float* __restrict__ Wr, const float* __restrict__ br,
                                                   float* __restrict__ h, float* __restrict__ part1) {
  __shared__ float Xt[64][16];
  __shared__ float et[64][10];
  int b = blockIdx.x, tid = threadIdx.x;
  int row0 = b * 64;
  int nr = NROWS - row0; if (nr > 64) nr = 64;

  for (int idx = tid; idx < nr * 10; idx += 192) {
    int r = idx / 10, c = idx - r * 10;
    et[r][c] = e[(size_t)(row0 + r) * 10 + c];
  }

  float acc[64];
#pragma unroll
  for (int r = 0; r < 64; ++r) acc[r] = 0.f;

  int j = tid;
  bool active = j < CAND;
  float bj = active ? br[j] : 0.f;

  for (int kk = 0; kk < DIM; kk += 16) {
    __syncthreads();
    for (int idx = tid; idx < nr * 16; idx += 192) {
      int r = idx >> 4, q = idx & 15;
      Xt[r][q] = X[(size_t)(row0 + r) * DIM + kk + q];
    }
    __syncthreads();
    if (active) {
#pragma unroll
      for (int q = 0; q < 16; q += 4) {
        float w0 = Wr[(kk + q) * CAND + j];
        float w1 = Wr[(kk + q + 1) * CAND + j];
        float w2 = Wr[(kk + q + 2) * CAND + j];
        float w3 = Wr[(kk + q + 3) * CAND + j];
#pragma unroll
        for (int r = 0; r < 64; ++r) {
          float x0v = Xt[r][q], x1v = Xt[r][q + 1], x2v = Xt[r][q + 2], x3v = Xt[r][q + 3];
          acc[r] = fmaf(x0v, w0, acc[r]);
          acc[r] = fmaf(x1v, w1, acc[r]);
          acc[r] = fmaf(x2v, w2, acc[r]);
          acc[r] = fmaf(x3v, w3, acc[r]);
        }
      }
    }
  }

  if (active) {
    float hh = 0.f;
    float eth[10];
#pragma unroll
    for (int c = 0; c < 10; ++c) eth[c] = 0.f;
    for (int r = 0; r < nr; ++r) {
      float z = acc[r] + bj;
      float hv = 1.0f / (1.0f + expf(-z));
      h[(size_t)(row0 + r) * CAND + j] = hv;
      hh = fmaf(hv, hv, hh);
#pragma unroll
      for (int c = 0; c < 10; ++c) eth[c] = fmaf(et[r][c], hv, eth[c]);
    }
    float* p = part1 + ((size_t)b * CAND + j) * 11;
    p[0] = hh;
#pragma unroll
    for (int c = 0; c < 10; ++c) p[1 + c] = eth[c];
  }
}

// reduce partials -> v per candidate -> argmax (first-index tie-break) -> record W col, b
__global__ __launch_bounds__(256) void score_pick_kern(const float* __restrict__ part1,
                                                       const float* __restrict__ Wr, const float* __restrict__ br,
                                                       float* __restrict__ outW, float* __restrict__ outb,
                                                       int* __restrict__ ibest, int k, int nblk) {
  __shared__ float sums[CAND * 11];
  __shared__ float sv[256];
  __shared__ int   si[256];
  __shared__ int   sbest;
  int tid = threadIdx.x;

  for (int idx = tid; idx < CAND * 11; idx += 256) {
    float s = 0.f;
    for (int b = 0; b < nblk; ++b) s += part1[(size_t)b * CAND * 11 + idx];
    sums[idx] = s;
  }
  __syncthreads();

  float v = -INFINITY; int bi = 0x7FFFFFFF;
  if (tid < CAND) {
    float hh = sums[tid * 11];
    float accv = 0.f;
#pragma unroll
    for (int c = 0; c < 10; ++c) { float d = sums[tid * 11 + 1 + c]; accv += (d * d) / hh; }
    v = accv / 10.0f;
    bi = tid;
  }
  sv[tid] = v; si[tid] = bi;
  __syncthreads();
  for (int s2 = 128; s2 > 0; s2 >>= 1) {
    if (tid < s2) {
      float v2 = sv[tid + s2]; int i2 = si[tid + s2];
      if (v2 > sv[tid] || (v2 == sv[tid] && i2 < si[tid])) { sv[tid] = v2; si[tid] = i2; }
    }
    __syncthreads();
  }
  if (tid == 0) { sbest = si[0]; *ibest = si[0]; }
  __syncthreads();
  int best = sbest;
  for (int i = tid; i < DIM; i += 256) outW[(size_t)i * KMAX + k] = Wr[(size_t)i * CAND + best];
  if (tid == 0) outb[k] = br[best];
}

// block j<k: r1[j] = Q[:,j] . h_c ; block j==k: gather H[:,k] = h[:,best]
__global__ __launch_bounds__(256) void qr_r1_kern(const float* __restrict__ h, float* __restrict__ Hm,
                                                  const float* __restrict__ Qm, float* __restrict__ r1g,
                                                  const int* __restrict__ ibest, int k) {
  int j = blockIdx.x, tid = threadIdx.x;
  int best = *ibest;
  if (j == k) {
    for (int i = tid; i < NROWS; i += 256)
      Hm[(size_t)k * NROWS + i] = h[(size_t)i * CAND + best];
  } else {
    float local = 0.f;
    for (int i = tid; i < NROWS; i += 256)
      local = fmaf(Qm[(size_t)j * NROWS + i], h[(size_t)i * CAND + best], local);
    local += __shfl_xor(local, 32); local += __shfl_xor(local, 16);
    local += __shfl_xor(local, 8);  local += __shfl_xor(local, 4);
    local += __shfl_xor(local, 2);  local += __shfl_xor(local, 1);
    __shared__ float wred[4];
    int wid = tid >> 6, lane = tid & 63;
    if (lane == 0) wred[wid] = local;
    __syncthreads();
    if (tid == 0) r1g[j] = wred[0] + wred[1] + wred[2] + wred[3];
  }
}

// t = h_c - Q r1 (stored unnormalized into Q[:,k]); partials: t.t, t^T Y; k==1 extras for normal eq.
__global__ __launch_bounds__(256) void qr_t_kern(const float* __restrict__ Hm, float* __restrict__ Qm,
                                                 const float* __restrict__ r1g, const float* __restrict__ Y,
                                                 float* __restrict__ part2, int k) {
  __shared__ float r1s[KMAX];
  int tid = threadIdx.x;
  for (int jj = tid; jj < k; jj += 256) r1s[jj] = r1g[jj];
  __syncthreads();

  int i = blockIdx.x * 256 + tid;
  float tval = 0.f, hc = 0.f, h0 = 0.f;
  float yv[10];
#pragma unroll
  for (int c = 0; c < 10; ++c) yv[c] = 0.f;

  if (i < NROWS) {
    hc = Hm[(size_t)k * NROWS + i];
    float s = 0.f;
    for (int jj = 0; jj < k; ++jj) s = fmaf(Qm[(size_t)jj * NROWS + i], r1s[jj], s);
    tval = hc - s;
    Qm[(size_t)k * NROWS + i] = tval;
#pragma unroll
    for (int c = 0; c < 10; ++c) yv[c] = Y[(size_t)i * 10 + c];
    if (k == 1) h0 = Hm[i];
  }

  float p[23];
  p[0] = tval * tval;
#pragma unroll
  for (int c = 0; c < 10; ++c) p[1 + c] = tval * yv[c];
  p[11] = hc * hc;
  p[12] = h0 * hc;
#pragma unroll
  for (int c = 0; c < 10; ++c) p[13 + c] = hc * yv[c];

  __shared__ float wred[4][23];
  int lane = tid & 63, wid = tid >> 6;
#pragma unroll
  for (int c = 0; c < 23; ++c) {
    float v = p[c];
    v += __shfl_xor(v, 32); v += __shfl_xor(v, 16); v += __shfl_xor(v, 8);
    v += __shfl_xor(v, 4);  v += __shfl_xor(v, 2);  v += __shfl_xor(v, 1);
    if (lane == 0) wred[wid][c] = v;
  }
  __syncthreads();
  if (tid < 23) part2[blockIdx.x * 23 + tid] = wred[0][tid] + wred[1][tid] + wred[2][tid] + wred[3][tid];
}

// finalize r2, R, QT; solve beta (normal eq for k<2, triangular solve for k>=2)
__global__ __launch_bounds__(256) void qr_fin_kern(const float* __restrict__ part2, const float* __restrict__ r1g,
                                                   float* __restrict__ Rm, float* __restrict__ QT,
                                                   float* __restrict__ scal, float* __restrict__ outBeta,
                                                   int k, int nblk) {
  __shared__ float vals[23];
  __shared__ float bsh[KMAX][10];
  int tid = threadIdx.x;
  if (tid < 23) {
    float s = 0.f;
    for (int b = 0; b < nblk; ++b) s += part2[b * 23 + tid];
    vals[tid] = s;
  }
  __syncthreads();
  float r2 = sqrtf(vals[0]);
  if (tid < k) Rm[tid * KMAX + k] = r1g[tid];
  if (tid == 0) { Rm[k * KMAX + k] = r2; scal[0] = r2; }
  if (tid < 10) QT[k * 10 + tid] = vals[1 + tid] / r2;
  if (k == 0 && tid < 11) scal[1 + tid] = vals[tid];   // g00, g0y[0..9]
  __syncthreads();

  if (k == 0) {
    if (tid < 10) outBeta[tid] = (1.0f / vals[0]) * vals[1 + tid];
  } else if (k == 1) {
    if (tid < 10) {
      float g00 = scal[1], g0y = scal[2 + tid];
      float s11 = vals[11], s01 = vals[12], s1y = vals[13 + tid];
      float det = g00 * s11 - s01 * s01;
      float i00 = s11 / det, i01 = -s01 / det, i11 = g00 / det;
      outBeta[tid]      = i00 * g0y + i01 * s1y;
      outBeta[10 + tid] = i01 * g0y + i11 * s1y;
    }
  } else {
    if (tid < 10) {
      for (int row = k; row >= 0; --row) {
        float s = QT[row * 10 + tid];
        for (int jj = row + 1; jj <= k; ++jj) s = fmaf(-Rm[row * KMAX + jj], bsh[jj][tid], s);
        float bv = s / Rm[row * KMAX + row];
        bsh[row][tid] = bv;
        outBeta[row * 10 + tid] = bv;
      }
    }
  }
}

// normalize Q[:,k] by r2; e = Y - H beta
__global__ __launch_bounds__(256) void update_e_kern(const float* __restrict__ Hm, float* __restrict__ Qm,
                                                     const float* __restrict__ Y, const float* __restrict__ beta,
                                                     float* __restrict__ e, const float* __restrict__ scal, int k) {
  int i = blockIdx.x * 256 + threadIdx.x;
  if (i >= NROWS) return;
  float r2 = scal[0];
  Qm[(size_t)k * NROWS + i] = Qm[(size_t)k * NROWS + i] / r2;
  float s[10];
#pragma unroll
  for (int c = 0; c < 10; ++c) s[c] = 0.f;
  for (int j = 0; j <= k; ++j) {
    float hv = Hm[(size_t)j * NROWS + i];
#pragma unroll
    for (int c = 0; c < 10; ++c) s[c] = fmaf(hv, beta[j * 10 + c], s[c]);
  }
#pragma unroll
  for (int c = 0; c < 10; ++c) e[(size_t)i * 10 + c] = Y[(size_t)i * 10 + c] - s[c];
}

// ---------------- host ----------------
extern "C" void kernel_launch(void* const* d_in, const int* in_sizes, int n_in,
                              void* d_out, int out_size, void* d_ws, size_t ws_size,
                              hipStream_t stream) {
  const float* X = (const float*)d_in[0];
  const float* Y = (const float*)d_in[1];
  float* out = (float*)d_out;
  float* outW    = out;                       // [784][64]
  float* outb    = out + (size_t)DIM * KMAX;  // [64]
  float* outBeta = outb + KMAX;               // [64][10]

  float* ws = (float*)d_ws;
  size_t off = 0;
  float* h    = ws + off; off += (size_t)NROWS * CAND;
  float* Wr   = ws + off; off += TOT_W;
  float* br   = ws + off; off += TOT_B;
  float* e    = ws + off; off += (size_t)NROWS * MOUT;
  float* Hm   = ws + off; off += (size_t)KMAX * NROWS;
  float* Qm   = ws + off; off += (size_t)KMAX * NROWS;
  float* Rm   = ws + off; off += (size_t)KMAX * KMAX;
  float* QT   = ws + off; off += (size_t)KMAX * MOUT;
  float* r1g  = ws + off; off += KMAX;
  float* part1 = ws + off; off += (size_t)GEMM_BLOCKS * CAND * 11;
  float* part2 = ws + off; off += (size_t)NB256 * 23;
  float* scal  = ws + off; off += 16;
  int*   ibest = (int*)(ws + off); off += 4;

  init_e_kern<<<(NROWS * MOUT + 255) / 256, 256, 0, stream>>>(Y, e);

  uint32_t key0 = 0u, key1 = 42u;
  for (int k = 0; k < KMAX; ++k) {
    // jax_threefry_partitionable=True split(key,3):
    // key t = threefry(key, counter (hi=0, lo=t)) output pair (o0, o1)
    uint32_t o0[3], o1[3];
    for (int t = 0; t < 3; ++t)
      threefry2x32(key0, key1, 0u, (uint32_t)t, &o0[t], &o1[t]);
    uint32_t kw0 = o0[1], kw1 = o1[1], kb0 = o0[2], kb1 = o1[2];
    key0 = o0[0]; key1 = o1[0];

    gen_rand_kern<<<(TOT_W + TOT_B + 255) / 256, 256, 0, stream>>>(Wr, br, kw0, kw1, kb0, kb1);
    gemm_h_kern<<<GEMM_BLOCKS, 192, 0, stream>>>(X, e, Wr, br, h, part1);
    score_pick_kern<<<1, 256, 0, stream>>>(part1, Wr, br, outW, outb, ibest, k, GEMM_BLOCKS);
    qr_r1_kern<<<k + 1, 256, 0, stream>>>(h, Hm, Qm, r1g, ibest, k);
    qr_t_kern<<<NB256, 256, 0, stream>>>(Hm, Qm, r1g, Y, part2, k);
    qr_fin_kern<<<1, 256, 0, stream>>>(part2, r1g, Rm, QT, scal, outBeta, k, NB256);
    update_e_kern<<<NB256, 256, 0, stream>>>(Hm, Qm, Y, outBeta, e, scal, k);
  }
}

// Round 3
// 35609.534 us; speedup vs baseline: 1.4850x; 1.4850x over previous
//
#include <hip/hip_runtime.h>
#include <cstdint>

#define NROWS 10000
#define DIM   784
#define CAND  150
#define MOUT  10
#define KMAX  64
#define TOT_W 117600   // DIM*CAND
#define TOT_B 150
#define BR 64          // rows per GEMM block
#define BC 160         // padded candidate cols
#define KT 16          // k tile
#define GEMM_BLOCKS 157   // ceil(10000/64)
#define NB256 40          // ceil(10000/256)

// ---------------- Threefry-2x32 (exact JAX partitionable semantics) ----------------
#define RND_(r) { x0 += x1; x1 = (x1 << r) | (x1 >> (32 - r)); x1 ^= x0; }

__host__ __device__ inline void threefry2x32(uint32_t k0, uint32_t k1,
                                             uint32_t c0, uint32_t c1,
                                             uint32_t* o0, uint32_t* o1) {
  uint32_t ks2 = 0x1BD11BDAu ^ k0 ^ k1;
  uint32_t x0 = c0 + k0, x1 = c1 + k1;
  RND_(13) RND_(15) RND_(26) RND_(6)
  x0 += k1;  x1 += ks2 + 1u;
  RND_(17) RND_(29) RND_(16) RND_(24)
  x0 += ks2; x1 += k0 + 2u;
  RND_(13) RND_(15) RND_(26) RND_(6)
  x0 += k0;  x1 += k1 + 3u;
  RND_(17) RND_(29) RND_(16) RND_(24)
  x0 += k1;  x1 += ks2 + 4u;
  RND_(13) RND_(15) RND_(26) RND_(6)
  x0 += ks2; x1 += k0 + 5u;
  *o0 = x0; *o1 = x1;
}

__device__ inline float uni01(uint32_t bits) {
  uint32_t fb = (bits >> 9) | 0x3F800000u;
  return __uint_as_float(fb) - 1.0f;
}

__device__ inline float scale_of(int j) {
  return (j < 50) ? 0.5f : ((j < 100) ? 1.0f : 5.0f);
}

// ---------------- kernels ----------------
__global__ __launch_bounds__(256) void init_e_kern(const float* __restrict__ Y, float* __restrict__ e) {
  int i = blockIdx.x * 256 + threadIdx.x;
  if (i < NROWS * MOUT) e[i] = Y[i];
}

__global__ __launch_bounds__(256) void gen_rand_kern(float* __restrict__ Wr, float* __restrict__ br,
                                                     uint32_t kw0, uint32_t kw1,
                                                     uint32_t kb0, uint32_t kb1) {
  int f = blockIdx.x * 256 + threadIdx.x;
  if (f < TOT_W) {
    uint32_t o0, o1;
    threefry2x32(kw0, kw1, 0u, (uint32_t)f, &o0, &o1);
    float u = uni01(o0 ^ o1);
    int j = f % CAND;
    Wr[f] = scale_of(j) * (2.0f * u - 1.0f);
  } else if (f < TOT_W + TOT_B) {
    int g = f - TOT_W;
    uint32_t o0, o1;
    threefry2x32(kb0, kb1, 0u, (uint32_t)g, &o0, &o1);
    float u = uni01(o0 ^ o1);
    br[g] = scale_of(g) * (2.0f * u - 1.0f);
  }
}

// Register-tiled GEMM: h = sigmoid(X@W + b), h stored column-major h_col[c*NROWS + row].
// Per-block partials of sum(h*h) and e^T h -> part1[block][c][11].
// k-accumulation order matches the validated kernel bitwise (sequential k per output).
__global__ __launch_bounds__(256) void gemm_h_kern(const float* __restrict__ X, const float* __restrict__ e,
                                                   const float* __restrict__ Wr, const float* __restrict__ br_,
                                                   float* __restrict__ h_col, float* __restrict__ part1) {
  // LDS: region A (Xt 16x64 | Wt 16x160) aliased later by red[4][160][11]; et separate.
  __shared__ __align__(16) float smem[7040];   // max(1024+2560, 4*1760) = 7040 floats
  __shared__ float et[BR][MOUT];
  float* Xt = smem;            // [KT][BR]
  float* Wt = smem + 1024;     // [KT][BC]
  float* red = smem;           // [4][BC*11]

  int tid = threadIdx.x;
  int ty = tid >> 5, tx = tid & 31;          // 8 x 32
  int row0 = blockIdx.x * BR;
  int nr = NROWS - row0; if (nr > BR) nr = BR;
  bool full = (nr == BR);

  // stage e tile once
  for (int idx = tid; idx < BR * MOUT; idx += 256) {
    int r = idx / MOUT, c = idx - r * MOUT;
    et[r][c] = (row0 + r < NROWS) ? e[(size_t)(row0 + r) * MOUT + c] : 0.f;
  }

  // bias per owned col
  float bbv[5];
#pragma unroll
  for (int cl = 0; cl < 5; ++cl) {
    int c = tx + 32 * cl;
    bbv[cl] = (c < CAND) ? br_[c] : 0.f;
  }

  float acc[8][5];
#pragma unroll
  for (int r = 0; r < 8; ++r)
#pragma unroll
    for (int cl = 0; cl < 5; ++cl) acc[r][cl] = 0.f;

  int rstage = tid >> 2;                 // 0..63
  int qg = (tid & 3) * 4;                // 0,4,8,12
  int rclamp = rstage < nr ? rstage : nr - 1;
  const float* Xrow = X + (size_t)(row0 + rclamp) * DIM;

  for (int kk = 0; kk < DIM; kk += KT) {
    __syncthreads();
    // stage X transposed: Xt[q][r]
    float4 xv4 = *(const float4*)(Xrow + kk + qg);
    Xt[(qg + 0) * BR + rstage] = xv4.x;
    Xt[(qg + 1) * BR + rstage] = xv4.y;
    Xt[(qg + 2) * BR + rstage] = xv4.z;
    Xt[(qg + 3) * BR + rstage] = xv4.w;
    // stage W: Wt[q][c], zero-pad c>=150
    for (int idx = tid; idx < KT * BC; idx += 256) {
      int q = idx / BC, c = idx - q * BC;
      Wt[idx] = (c < CAND) ? Wr[(size_t)(kk + q) * CAND + c] : 0.f;
    }
    __syncthreads();
#pragma unroll
    for (int q = 0; q < KT; ++q) {
      float xv[8];
      *(float4*)&xv[0] = *(const float4*)&Xt[q * BR + ty * 8];
      *(float4*)&xv[4] = *(const float4*)&Xt[q * BR + ty * 8 + 4];
      float wv[5];
#pragma unroll
      for (int cl = 0; cl < 5; ++cl) wv[cl] = Wt[q * BC + tx + 32 * cl];
#pragma unroll
      for (int r = 0; r < 8; ++r)
#pragma unroll
        for (int cl = 0; cl < 5; ++cl)
          acc[r][cl] = fmaf(xv[r], wv[cl], acc[r][cl]);
    }
  }

  __syncthreads();   // Xt/Wt dead; red region may now be written

  // epilogue per owned column
#pragma unroll
  for (int cl = 0; cl < 5; ++cl) {
    int c = tx + 32 * cl;
    float hv[8];
#pragma unroll
    for (int r = 0; r < 8; ++r)
      hv[r] = 1.0f / (1.0f + expf(-(acc[r][cl] + bbv[cl])));
    if (c < CAND) {
      float* dst = h_col + (size_t)c * NROWS + row0 + ty * 8;
      if (full) {
        float4 a = {hv[0], hv[1], hv[2], hv[3]};
        float4 b = {hv[4], hv[5], hv[6], hv[7]};
        *(float4*)dst = a;
        *(float4*)(dst + 4) = b;
      } else {
#pragma unroll
        for (int r = 0; r < 8; ++r)
          if (ty * 8 + r < nr) dst[r] = hv[r];
      }
    }
    float hh = 0.f, eth[10];
#pragma unroll
    for (int j = 0; j < 10; ++j) eth[j] = 0.f;
#pragma unroll
    for (int r = 0; r < 8; ++r) {
      if (full || ty * 8 + r < nr) {
        hh = fmaf(hv[r], hv[r], hh);
#pragma unroll
        for (int j = 0; j < 10; ++j) eth[j] = fmaf(et[ty * 8 + r][j], hv[r], eth[j]);
      }
    }
    // reduce ty pairs (lanes tx <-> tx+32 within wave)
    hh += __shfl_xor(hh, 32);
#pragma unroll
    for (int j = 0; j < 10; ++j) eth[j] += __shfl_xor(eth[j], 32);
    if (!(ty & 1) && c < CAND) {
      float* dstr = red + (ty >> 1) * 1760 + c * 11;
      dstr[0] = hh;
#pragma unroll
      for (int j = 0; j < 10; ++j) dstr[1 + j] = eth[j];
    }
  }
  __syncthreads();
  for (int idx = tid; idx < CAND * 11; idx += 256) {
    float s = red[idx] + red[1760 + idx] + red[3520 + idx] + red[5280 + idx];
    part1[(size_t)blockIdx.x * (CAND * 11) + idx] = s;
  }
}

// reduce partials -> v per candidate -> argmax (first-index tie-break) -> record W col, b
__global__ __launch_bounds__(256) void score_pick_kern(const float* __restrict__ part1,
                                                       const float* __restrict__ Wr, const float* __restrict__ br,
                                                       float* __restrict__ outW, float* __restrict__ outb,
                                                       int* __restrict__ ibest, int k, int nblk) {
  __shared__ float sums[CAND * 11];
  __shared__ float sv[256];
  __shared__ int   si[256];
  __shared__ int   sbest;
  int tid = threadIdx.x;

  for (int idx = tid; idx < CAND * 11; idx += 256) {
    float s = 0.f;
    for (int b = 0; b < nblk; ++b) s += part1[(size_t)b * CAND * 11 + idx];
    sums[idx] = s;
  }
  __syncthreads();

  float v = -INFINITY; int bi = 0x7FFFFFFF;
  if (tid < CAND) {
    float hh = sums[tid * 11];
    float accv = 0.f;
#pragma unroll
    for (int c = 0; c < 10; ++c) { float d = sums[tid * 11 + 1 + c]; accv += (d * d) / hh; }
    v = accv / 10.0f;
    bi = tid;
  }
  sv[tid] = v; si[tid] = bi;
  __syncthreads();
  for (int s2 = 128; s2 > 0; s2 >>= 1) {
    if (tid < s2) {
      float v2 = sv[tid + s2]; int i2 = si[tid + s2];
      if (v2 > sv[tid] || (v2 == sv[tid] && i2 < si[tid])) { sv[tid] = v2; si[tid] = i2; }
    }
    __syncthreads();
  }
  if (tid == 0) { sbest = si[0]; *ibest = si[0]; }
  __syncthreads();
  int best = sbest;
  for (int i = tid; i < DIM; i += 256) outW[(size_t)i * KMAX + k] = Wr[(size_t)i * CAND + best];
  if (tid == 0) outb[k] = br[best];
}

// block j<k: r1[j] = Q[:,j] . h_c ; block j==k: copy H[:,k] = h_col[:,best]
__global__ __launch_bounds__(256) void qr_r1_kern(const float* __restrict__ h_col, float* __restrict__ Hm,
                                                  const float* __restrict__ Qm, float* __restrict__ r1g,
                                                  const int* __restrict__ ibest, int k) {
  int j = blockIdx.x, tid = threadIdx.x;
  int best = *ibest;
  const float* hc = h_col + (size_t)best * NROWS;
  if (j == k) {
    for (int i = tid; i < NROWS; i += 256)
      Hm[(size_t)k * NROWS + i] = hc[i];
  } else {
    float local = 0.f;
    for (int i = tid; i < NROWS; i += 256)
      local = fmaf(Qm[(size_t)j * NROWS + i], hc[i], local);
    local += __shfl_xor(local, 32); local += __shfl_xor(local, 16);
    local += __shfl_xor(local, 8);  local += __shfl_xor(local, 4);
    local += __shfl_xor(local, 2);  local += __shfl_xor(local, 1);
    __shared__ float wred[4];
    int wid = tid >> 6, lane = tid & 63;
    if (lane == 0) wred[wid] = local;
    __syncthreads();
    if (tid == 0) r1g[j] = wred[0] + wred[1] + wred[2] + wred[3];
  }
}

// t = h_c - Q r1 (stored unnormalized into Q[:,k]); partials: t.t, t^T Y; k==1 extras.
__global__ __launch_bounds__(256) void qr_t_kern(const float* __restrict__ Hm, float* __restrict__ Qm,
                                                 const float* __restrict__ r1g, const float* __restrict__ Y,
                                                 float* __restrict__ part2, int k) {
  __shared__ float r1s[KMAX];
  int tid = threadIdx.x;
  for (int jj = tid; jj < k; jj += 256) r1s[jj] = r1g[jj];
  __syncthreads();

  int i = blockIdx.x * 256 + tid;
  float tval = 0.f, hc = 0.f, h0 = 0.f;
  float yv[10];
#pragma unroll
  for (int c = 0; c < 10; ++c) yv[c] = 0.f;

  if (i < NROWS) {
    hc = Hm[(size_t)k * NROWS + i];
    float s = 0.f;
    for (int jj = 0; jj < k; ++jj) s = fmaf(Qm[(size_t)jj * NROWS + i], r1s[jj], s);
    tval = hc - s;
    Qm[(size_t)k * NROWS + i] = tval;
#pragma unroll
    for (int c = 0; c < 10; ++c) yv[c] = Y[(size_t)i * 10 + c];
    if (k == 1) h0 = Hm[i];
  }

  float p[23];
  p[0] = tval * tval;
#pragma unroll
  for (int c = 0; c < 10; ++c) p[1 + c] = tval * yv[c];
  p[11] = hc * hc;
  p[12] = h0 * hc;
#pragma unroll
  for (int c = 0; c < 10; ++c) p[13 + c] = hc * yv[c];

  __shared__ float wred[4][23];
  int lane = tid & 63, wid = tid >> 6;
#pragma unroll
  for (int c = 0; c < 23; ++c) {
    float v = p[c];
    v += __shfl_xor(v, 32); v += __shfl_xor(v, 16); v += __shfl_xor(v, 8);
    v += __shfl_xor(v, 4);  v += __shfl_xor(v, 2);  v += __shfl_xor(v, 1);
    if (lane == 0) wred[wid][c] = v;
  }
  __syncthreads();
  if (tid < 23) part2[blockIdx.x * 23 + tid] = wred[0][tid] + wred[1][tid] + wred[2][tid] + wred[3][tid];
}

// finalize r2, R, QT; solve beta (normal eq for k<2, triangular solve for k>=2)
__global__ __launch_bounds__(256) void qr_fin_kern(const float* __restrict__ part2, const float* __restrict__ r1g,
                                                   float* __restrict__ Rm, float* __restrict__ QT,
                                                   float* __restrict__ scal, float* __restrict__ outBeta,
                                                   int k, int nblk) {
  __shared__ float vals[23];
  __shared__ float bsh[KMAX][10];
  int tid = threadIdx.x;
  if (tid < 23) {
    float s = 0.f;
    for (int b = 0; b < nblk; ++b) s += part2[b * 23 + tid];
    vals[tid] = s;
  }
  __syncthreads();
  float r2 = sqrtf(vals[0]);
  if (tid < k) Rm[tid * KMAX + k] = r1g[tid];
  if (tid == 0) { Rm[k * KMAX + k] = r2; scal[0] = r2; }
  if (tid < 10) QT[k * 10 + tid] = vals[1 + tid] / r2;
  if (k == 0 && tid < 11) scal[1 + tid] = vals[tid];
  __syncthreads();

  if (k == 0) {
    if (tid < 10) outBeta[tid] = (1.0f / vals[0]) * vals[1 + tid];
  } else if (k == 1) {
    if (tid < 10) {
      float g00 = scal[1], g0y = scal[2 + tid];
      float s11 = vals[11], s01 = vals[12], s1y = vals[13 + tid];
      float det = g00 * s11 - s01 * s01;
      float i00 = s11 / det, i01 = -s01 / det, i11 = g00 / det;
      outBeta[tid]      = i00 * g0y + i01 * s1y;
      outBeta[10 + tid] = i01 * g0y + i11 * s1y;
    }
  } else {
    if (tid < 10) {
      for (int row = k; row >= 0; --row) {
        float s = QT[row * 10 + tid];
        for (int jj = row + 1; jj <= k; ++jj) s = fmaf(-Rm[row * KMAX + jj], bsh[jj][tid], s);
        float bv = s / Rm[row * KMAX + row];
        bsh[row][tid] = bv;
        outBeta[row * 10 + tid] = bv;
      }
    }
  }
}

// normalize Q[:,k] by r2; e = Y - H beta
__global__ __launch_bounds__(256) void update_e_kern(const float* __restrict__ Hm, float* __restrict__ Qm,
                                                     const float* __restrict__ Y, const float* __restrict__ beta,
                                                     float* __restrict__ e, const float* __restrict__ scal, int k) {
  int i = blockIdx.x * 256 + threadIdx.x;
  if (i >= NROWS) return;
  float r2 = scal[0];
  Qm[(size_t)k * NROWS + i] = Qm[(size_t)k * NROWS + i] / r2;
  float s[10];
#pragma unroll
  for (int c = 0; c < 10; ++c) s[c] = 0.f;
  for (int j = 0; j <= k; ++j) {
    float hv = Hm[(size_t)j * NROWS + i];
#pragma unroll
    for (int c = 0; c < 10; ++c) s[c] = fmaf(hv, beta[j * 10 + c], s[c]);
  }
#pragma unroll
  for (int c = 0; c < 10; ++c) e[(size_t)i * 10 + c] = Y[(size_t)i * 10 + c] - s[c];
}

// ---------------- host ----------------
extern "C" void kernel_launch(void* const* d_in, const int* in_sizes, int n_in,
                              void* d_out, int out_size, void* d_ws, size_t ws_size,
                              hipStream_t stream) {
  const float* X = (const float*)d_in[0];
  const float* Y = (const float*)d_in[1];
  float* out = (float*)d_out;
  float* outW    = out;
  float* outb    = out + (size_t)DIM * KMAX;
  float* outBeta = outb + KMAX;

  float* ws = (float*)d_ws;
  size_t off = 0;
  float* h_col = ws + off; off += (size_t)NROWS * CAND;
  float* Wr   = ws + off; off += TOT_W;
  float* br   = ws + off; off += TOT_B;
  float* e    = ws + off; off += (size_t)NROWS * MOUT;
  float* Hm   = ws + off; off += (size_t)KMAX * NROWS;
  float* Qm   = ws + off; off += (size_t)KMAX * NROWS;
  float* Rm   = ws + off; off += (size_t)KMAX * KMAX;
  float* QT   = ws + off; off += (size_t)KMAX * MOUT;
  float* r1g  = ws + off; off += KMAX;
  float* part1 = ws + off; off += (size_t)GEMM_BLOCKS * CAND * 11;
  float* part2 = ws + off; off += (size_t)NB256 * 23;
  float* scal  = ws + off; off += 16;
  int*   ibest = (int*)(ws + off); off += 4;

  init_e_kern<<<(NROWS * MOUT + 255) / 256, 256, 0, stream>>>(Y, e);

  uint32_t key0 = 0u, key1 = 42u;
  for (int k = 0; k < KMAX; ++k) {
    uint32_t o0[3], o1[3];
    for (int t = 0; t < 3; ++t)
      threefry2x32(key0, key1, 0u, (uint32_t)t, &o0[t], &o1[t]);
    uint32_t kw0 = o0[1], kw1 = o1[1], kb0 = o0[2], kb1 = o1[2];
    key0 = o0[0]; key1 = o1[0];

    gen_rand_kern<<<(TOT_W + TOT_B + 255) / 256, 256, 0, stream>>>(Wr, br, kw0, kw1, kb0, kb1);
    gemm_h_kern<<<GEMM_BLOCKS, 256, 0, stream>>>(X, e, Wr, br, h_col, part1);
    score_pick_kern<<<1, 256, 0, stream>>>(part1, Wr, br, outW, outb, ibest, k, GEMM_BLOCKS);
    qr_r1_kern<<<k + 1, 256, 0, stream>>>(h_col, Hm, Qm, r1g, ibest, k);
    qr_t_kern<<<NB256, 256, 0, stream>>>(Hm, Qm, r1g, Y, part2, k);
    qr_fin_kern<<<1, 256, 0, stream>>>(part2, r1g, Rm, QT, scal, outBeta, k, NB256);
    update_e_kern<<<NB256, 256, 0, stream>>>(Hm, Qm, Y, outBeta, e, scal, k);
  }
}